// Round 11
// baseline (314.201 us; speedup 1.0000x reference)
//
#include <hip/hip_runtime.h>
#include <hip/hip_bf16.h>

// ---------------- problem constants ----------------
#define Bn 16
#define Tn 256
#define Fn 128
#define Cn 32
#define Dn 32
#define EPSf 1e-5f
#define SELU_L 1.0507009873554805f
#define SELU_A 1.6732632423543772f

typedef unsigned short u16;
typedef unsigned int u32;
typedef __attribute__((ext_vector_type(8))) short bf16x8;
typedef __attribute__((ext_vector_type(4))) float f32x4;

struct Ptrs { const void* p[39]; };

// ---------------- param offsets (floats, in ws) ----------------
#define P_C1W 0          // 1024
#define P_C1B 1024       // 32
#define P_MW  1056       // 32  (= c2w*bnA*selu_lambda)
#define P_MK  1088       // 1
#define P_FC  1089       // gat block, 3264 floats
#define P_TCG (1089+3264)
// gat block internal
#define G_APW 0
#define G_APB 1024
#define G_AW  1056
#define G_PWW 1088
#define G_PWB 2112
#define G_POW 2144
#define G_POB 3168
#define G_GS  3200
#define G_GB  3232
#define GAT_SZ 3264
#define P_PFW (P_TCG+GAT_SZ)   // 32
#define P_PFB (P_PFW+32)       // 1
#define P_PTW (P_PFB+1)        // 32
#define P_PTB (P_PTW+32)       // 1
#define P_W1  (P_PTB+1)        // 1024
#define P_W2  (P_W1+1024)      // 1024
#define P_FCW (P_W2+1024)      // 128
#define P_FCB (P_FCW+128)      // 2
#define P_FLAG 10000           // 1.0 if inputs are bf16, 0.0 if fp32

// ---------------- ws layout (floats) ----------------
#define WS_M     10240                    // 524288
#define WS_FCATT (WS_M+524288)            // 65536   (B,128,32)
#define WS_TCATT (WS_FCATT+65536)         // 131072  (B,256,32)
#define WS_FCGAT (WS_TCATT+131072)        // 65536
#define WS_TCGAT (WS_FCGAT+65536)         // 131072
#define WS_XF    (WS_TCGAT+131072)        // 32768   (B,64,32)
#define WS_XT    (WS_XF+32768)            // 65536   (B,128,32)
#define WS_XFF   (WS_XT+65536)            // 32768
#define WS_XTF   (WS_XFF+32768)           // 65536

// ---------------- helpers ----------------
__device__ __forceinline__ float bf2f(u16 u) {
    union { u32 i; float f; } v; v.i = ((u32)u) << 16; return v.f;
}
__device__ __forceinline__ u16 f2bf(float f) {
    union { float f; u32 u; } v; v.f = f;
    u32 r = (v.u + 0x7fffu + ((v.u >> 16) & 1u)) >> 16;
    return (u16)r;
}
__device__ __forceinline__ u32 cvt_pk_bf16(float lo, float hi) {
    u32 r;
    asm("v_cvt_pk_bf16_f32 %0, %1, %2" : "=v"(r) : "v"(lo), "v"(hi));
    return r;
}
__device__ __forceinline__ void up2(u32 u, float* o) {
    union { u32 i; float f; } a, b;
    a.i = u << 16; b.i = u & 0xffff0000u;
    o[0] = a.f; o[1] = b.f;
}
__device__ __forceinline__ float tanh_fast(float x) {
    float e = __expf(2.f * x);
    return 1.f - 2.f / (e + 1.f);
}
__device__ __forceinline__ float ldp(const void* p, int i, int isb) {
    return isb ? bf2f(((const u16*)p)[i]) : ((const float*)p)[i];
}

// ---------------- K0: detect dtype + convert/fold params (parallel, 4 blocks) ----------------
__global__ __launch_bounds__(256) void k0_setup(Ptrs in, float* __restrict__ P) {
    __shared__ int sflag;
    int tid = threadIdx.x;
    int blk = blockIdx.x;
    if (tid < 64) {
        const u16* xu = (const u16*)in.p[0];
        int bad = 0;
        #pragma unroll
        for (int q = 0; q < 4; q++) {
            float f = bf2f(xu[tid * 4 + q]);
            float a = fabsf(f);
            if (!(a < 64.f) && !(a == 0.f)) bad++;
        }
        #pragma unroll
        for (int off = 32; off >= 1; off >>= 1) bad += __shfl_xor(bad, off, 64);
        if (tid == 0) sflag = (bad <= 8) ? 1 : 0;
    }
    __syncthreads();
    const int isb = sflag;

    if (blk == 0) {
        if (tid == 0) P[P_FLAG] = (float)isb;
        for (int i = tid; i < 1024; i += 256) P[P_C1W + i] = ldp(in.p[1], i, isb);
        if (tid < 32) {
            float A = ldp(in.p[3], tid, isb) * rsqrtf(ldp(in.p[6], tid, isb) + EPSf);
            float w = ldp(in.p[7], tid, isb);
            P[P_C1B + tid] = ldp(in.p[2], tid, isb);
            P[P_MW + tid] = w * A * SELU_L;
            float Bc = ldp(in.p[4], tid, isb) - ldp(in.p[5], tid, isb) * A;
            float term = w * Bc;
            #pragma unroll
            for (int off = 16; off >= 1; off >>= 1) term += __shfl_xor(term, off, 64);
            if (tid == 0) P[P_MK] = term + ldp(in.p[8], 0, isb);
        }
        if (tid >= 64 && tid < 96) {
            int t = tid - 64;
            P[P_PFW + t] = ldp(in.p[31], t, isb);
            P[P_PTW + t] = ldp(in.p[33], t, isb);
        }
        if (tid == 96) { P[P_PFB] = ldp(in.p[32], 0, isb); P[P_PTB] = ldp(in.p[34], 0, isb); }
        if (tid == 97) P[P_FCB]     = ldp(in.p[38], 0, isb);
        if (tid == 98) P[P_FCB + 1] = ldp(in.p[38], 1, isb);
        if (tid >= 128) P[P_FCW + (tid - 128)] = ldp(in.p[37], tid - 128, isb);
    } else if (blk <= 2) {
        int g = blk - 1;
        int ib = g ? 20 : 9;
        float* G = P + (g ? P_TCG : P_FC);
        for (int i = tid; i < 1024; i += 256) {
            G[G_APW + i] = ldp(in.p[ib + 0], i, isb);
            G[G_PWW + i] = ldp(in.p[ib + 3], i, isb);
            G[G_POW + i] = ldp(in.p[ib + 5], i, isb);
        }
        if (tid < 32) {
            G[G_APB + tid] = ldp(in.p[ib + 1], tid, isb);
            G[G_AW  + tid] = ldp(in.p[ib + 2], tid, isb);
            G[G_PWB + tid] = ldp(in.p[ib + 4], tid, isb);
            G[G_POB + tid] = ldp(in.p[ib + 6], tid, isb);
            float gs = ldp(in.p[ib + 7], tid, isb) * rsqrtf(ldp(in.p[ib + 10], tid, isb) + EPSf);
            G[G_GS + tid] = gs;
            G[G_GB + tid] = ldp(in.p[ib + 8], tid, isb) - ldp(in.p[ib + 9], tid, isb) * gs;
        }
    } else {
        for (int i = tid; i < 1024; i += 256) {
            P[P_W1 + i] = ldp(in.p[35], i, isb);
            P[P_W2 + i] = ldp(in.p[36], i, isb);
        }
    }
}

// ---------------- K1: conv1 + SELU + BN + conv2 -> m (MFMA, transposed epilogue) ----------------
__global__ __launch_bounds__(256) void k1_conv_m(const void* __restrict__ xin,
                                                 const float* __restrict__ P,
                                                 float* __restrict__ M) {
    const int isb = __builtin_amdgcn_readfirstlane((int)P[P_FLAG]);
    int tid = threadIdx.x;
    if (isb) {
        int w = tid >> 6, lane = tid & 63;
        int n = lane & 15, g = lane >> 4, kc = g * 8;
        union { u32 u[4]; bf16x8 v; } B0, B1;
        #pragma unroll
        for (int e = 0; e < 4; e++) {
            B0.u[e] = cvt_pk_bf16(P[P_C1W + n * 32 + kc + 2 * e],
                                  P[P_C1W + n * 32 + kc + 2 * e + 1]);
            B1.u[e] = cvt_pk_bf16(P[P_C1W + (n + 16) * 32 + kc + 2 * e],
                                  P[P_C1W + (n + 16) * 32 + kc + 2 * e + 1]);
        }
        float cb0v[4], cb1v[4], mw0v[4], mw1v[4];
        #pragma unroll
        for (int r = 0; r < 4; r++) {
            cb0v[r] = P[P_C1B + g * 4 + r];
            cb1v[r] = P[P_C1B + 16 + g * 4 + r];
            mw0v[r] = P[P_MW + g * 4 + r];
            mw1v[r] = P[P_MW + 16 + g * 4 + r];
        }
        float mk = P[P_MK];
        int rowblk = blockIdx.x * 256 + w * 64;
        const u16* xp = (const u16*)xin + (size_t)rowblk * 32;
        bf16x8 a[4];
        #pragma unroll
        for (int s = 0; s < 4; s++)
            a[s] = *(const bf16x8*)(xp + ((size_t)s * 16 + n) * 32 + kc);
        #pragma unroll
        for (int s = 0; s < 4; s++) {
            f32x4 c0 = {0.f, 0.f, 0.f, 0.f}, c1 = {0.f, 0.f, 0.f, 0.f};
            c0 = __builtin_amdgcn_mfma_f32_16x16x32_bf16(B0.v, a[s], c0, 0, 0, 0);
            c1 = __builtin_amdgcn_mfma_f32_16x16x32_bf16(B1.v, a[s], c1, 0, 0, 0);
            float part = 0.f;
            #pragma unroll
            for (int r = 0; r < 4; r++) {
                float z0 = c0[r] + cb0v[r], z1 = c1[r] + cb1v[r];
                float s0 = (z0 > 0.f) ? z0 : SELU_A * (__expf(z0) - 1.f);
                float s1 = (z1 > 0.f) ? z1 : SELU_A * (__expf(z1) - 1.f);
                part = fmaf(mw0v[r], s0, part);
                part = fmaf(mw1v[r], s1, part);
            }
            part += __shfl_xor(part, 16, 64);
            part += __shfl_xor(part, 32, 64);
            if (lane < 16) M[(size_t)rowblk + s * 16 + n] = part + mk;
        }
    } else {
        int idx = blockIdx.x * 256 + tid;
        float xv[32];
        const float4* xf4 = reinterpret_cast<const float4*>((const float*)xin + (size_t)idx * 32);
        #pragma unroll
        for (int q = 0; q < 8; q++) {
            float4 v = xf4[q];
            xv[q * 4 + 0] = v.x; xv[q * 4 + 1] = v.y;
            xv[q * 4 + 2] = v.z; xv[q * 4 + 3] = v.w;
        }
        float acc = P[P_MK];
        #pragma unroll
        for (int o = 0; o < 32; o++) {
            float z = P[P_C1B + o];
            #pragma unroll
            for (int c = 0; c < 32; c++) z = fmaf(P[P_C1W + o * 32 + c], xv[c], z);
            float br = (z > 0.f) ? z : SELU_A * (__expf(z) - 1.f);
            acc = fmaf(P[P_MW + o], br, acc);
        }
        M[idx] = acc;
    }
}

// ---------------- K2: softmax over T + zero FCatt (128 blocks, float4, 3 barriers) ----------------
__global__ __launch_bounds__(256) void k2_softmax(float* __restrict__ M,
                                                  float* __restrict__ FCzero) {
    __shared__ float wred[4][16];
    int b = blockIdx.x >> 3, fg = blockIdx.x & 7;
    int tid = threadIdx.x;
    int w = tid >> 6, lane = tid & 63;
    int fq = tid & 3, tt = tid >> 2;
    float* colb = M + (size_t)b * (Tn * Fn) + fg * 16 + fq * 4;
    float4 v[4];
    float mx[4] = {-1e30f, -1e30f, -1e30f, -1e30f};
    #pragma unroll
    for (int p = 0; p < 4; p++) {
        v[p] = *(float4*)(colb + (size_t)(tt + p * 64) * Fn);
        mx[0] = fmaxf(mx[0], v[p].x); mx[1] = fmaxf(mx[1], v[p].y);
        mx[2] = fmaxf(mx[2], v[p].z); mx[3] = fmaxf(mx[3], v[p].w);
    }
    #pragma unroll
    for (int off = 4; off <= 32; off <<= 1) {
        #pragma unroll
        for (int c = 0; c < 4; c++) mx[c] = fmaxf(mx[c], __shfl_xor(mx[c], off, 64));
    }
    if (lane < 4) {
        #pragma unroll
        for (int c = 0; c < 4; c++) wred[w][lane * 4 + c] = mx[c];
    }
    __syncthreads();
    #pragma unroll
    for (int c = 0; c < 4; c++)
        mx[c] = fmaxf(fmaxf(wred[0][fq * 4 + c], wred[1][fq * 4 + c]),
                      fmaxf(wred[2][fq * 4 + c], wred[3][fq * 4 + c]));
    float4 e[4];
    float sm[4] = {0.f, 0.f, 0.f, 0.f};
    #pragma unroll
    for (int p = 0; p < 4; p++) {
        e[p].x = __expf(v[p].x - mx[0]); sm[0] += e[p].x;
        e[p].y = __expf(v[p].y - mx[1]); sm[1] += e[p].y;
        e[p].z = __expf(v[p].z - mx[2]); sm[2] += e[p].z;
        e[p].w = __expf(v[p].w - mx[3]); sm[3] += e[p].w;
    }
    #pragma unroll
    for (int off = 4; off <= 32; off <<= 1) {
        #pragma unroll
        for (int c = 0; c < 4; c++) sm[c] += __shfl_xor(sm[c], off, 64);
    }
    __syncthreads();
    if (lane < 4) {
        #pragma unroll
        for (int c = 0; c < 4; c++) wred[w][lane * 4 + c] = sm[c];
    }
    __syncthreads();
    float inv[4];
    #pragma unroll
    for (int c = 0; c < 4; c++)
        inv[c] = 1.f / (wred[0][fq * 4 + c] + wred[1][fq * 4 + c] +
                        wred[2][fq * 4 + c] + wred[3][fq * 4 + c]);
    #pragma unroll
    for (int p = 0; p < 4; p++) {
        float4 o4 = make_float4(e[p].x * inv[0], e[p].y * inv[1],
                                e[p].z * inv[2], e[p].w * inv[3]);
        *(float4*)(colb + (size_t)(tt + p * 64) * Fn) = o4;
    }
    int gid = blockIdx.x * 256 + tid;
    for (int i = gid; i < Bn * Fn * Cn; i += 128 * 256) FCzero[i] = 0.f;
}

// ---------------- K3: FCatt + TCatt — 16B loads, LDS transpose, contiguous atomics ----------------
// Loads: round-6 mapping (thread = f0=tid>>2, cc=(tid&3)*8; bf16x8 = 16B per row-half).
// Atomics: round-5 contiguous layout (tid*2+512k -> 2 cachelines per wave-instr),
// bridged by a 16 KB LDS transpose (thread-linear float4 writes, float2 reads).
__global__ __launch_bounds__(256) void k3n(const void* __restrict__ xin,
                                           const float* __restrict__ M,
                                           const float* __restrict__ Pflag,
                                           float* __restrict__ FCatt,
                                           float* __restrict__ TCatt) {
    __shared__ float part[4][8][32];     // [wave][tt][c]
    __shared__ __align__(16) float sh[4096];
    int bi = blockIdx.x;                 // 512 blocks: b*32 + tg (8 t's each)
    int b = bi >> 5, tg = bi & 31;
    int tid = threadIdx.x;
    int w = tid >> 6, lane = tid & 63;
    int cc = (tid & 3) * 8, f0 = tid >> 2;
    const int isb = __builtin_amdgcn_readfirstlane((int)Pflag[P_FLAG]);
    float fa0[8], fa1[8];
    #pragma unroll
    for (int e = 0; e < 8; e++) { fa0[e] = 0.f; fa1[e] = 0.f; }
    for (int tt = 0; tt < 8; tt++) {
        int t = tg * 8 + tt;
        const float* Mrow = M + (size_t)b * (Tn * Fn) + (size_t)t * Fn;
        float m0 = Mrow[f0], m1 = Mrow[f0 + 64];
        size_t rowoff = ((size_t)b * Tn + t) * (Fn * Cn);
        float xv0[8], xv1[8];
        if (isb) {
            const u16* xr = (const u16*)xin + rowoff + f0 * 32 + cc;
            union { u32 u[4]; bf16x8 v; } q0, q1;
            q0.v = *(const bf16x8*)xr;
            q1.v = *(const bf16x8*)(xr + 64 * 32);
            up2(q0.u[0], xv0 + 0); up2(q0.u[1], xv0 + 2);
            up2(q0.u[2], xv0 + 4); up2(q0.u[3], xv0 + 6);
            up2(q1.u[0], xv1 + 0); up2(q1.u[1], xv1 + 2);
            up2(q1.u[2], xv1 + 4); up2(q1.u[3], xv1 + 6);
        } else {
            const float* xr = (const float*)xin + rowoff + f0 * 32 + cc;
            float4 a0 = *(const float4*)xr, a1 = *(const float4*)(xr + 4);
            float4 b0 = *(const float4*)(xr + 64 * 32), b1 = *(const float4*)(xr + 64 * 32 + 4);
            xv0[0] = a0.x; xv0[1] = a0.y; xv0[2] = a0.z; xv0[3] = a0.w;
            xv0[4] = a1.x; xv0[5] = a1.y; xv0[6] = a1.z; xv0[7] = a1.w;
            xv1[0] = b0.x; xv1[1] = b0.y; xv1[2] = b0.z; xv1[3] = b0.w;
            xv1[4] = b1.x; xv1[5] = b1.y; xv1[6] = b1.z; xv1[7] = b1.w;
        }
        float tp[8];
        #pragma unroll
        for (int e = 0; e < 8; e++) {
            float p0 = xv0[e] * m0, p1 = xv1[e] * m1;
            fa0[e] += p0; fa1[e] += p1;
            tp[e] = p0 + p1;
        }
        #pragma unroll
        for (int off = 4; off <= 32; off <<= 1) {
            #pragma unroll
            for (int e = 0; e < 8; e++) tp[e] += __shfl_xor(tp[e], off, 64);
        }
        if (lane < 4) {
            #pragma unroll
            for (int e = 0; e < 8; e++) part[w][tt][lane * 8 + e] = tp[e];
        }
    }
    // stage FCatt partials to LDS, thread-linear (fa0[e] belongs at 8*tid+e; fa1 at +2048)
    float4* sh4 = (float4*)sh;
    sh4[tid * 2]       = make_float4(fa0[0], fa0[1], fa0[2], fa0[3]);
    sh4[tid * 2 + 1]   = make_float4(fa0[4], fa0[5], fa0[6], fa0[7]);
    sh4[512 + tid * 2]     = make_float4(fa1[0], fa1[1], fa1[2], fa1[3]);
    sh4[512 + tid * 2 + 1] = make_float4(fa1[4], fa1[5], fa1[6], fa1[7]);
    __syncthreads();
    {
        int tt = tid >> 5, c = tid & 31;
        float s = part[0][tt][c] + part[1][tt][c] + part[2][tt][c] + part[3][tt][c];
        TCatt[((size_t)b * Tn + tg * 8 + tt) * Cn + c] = s;
    }
    // contiguous atomics (round-5 layout): wave-instr covers 128 consecutive floats
    #pragma unroll
    for (int k = 0; k < 8; k++) {
        float2 v = *(float2*)&sh[tid * 2 + 512 * k];
        atomicAdd(&FCatt[(size_t)b * 4096 + tid * 2 + 512 * k],     v.x);
        atomicAdd(&FCatt[(size_t)b * 4096 + tid * 2 + 512 * k + 1], v.y);
    }
}

// ---------------- K4ab: fused GAT — every wave owns 4 j-tiles; 2/4-partial combine ----------------
// FC: 2 waves/row (1024 blocks = 16b x 64 row-pairs). TC: 4 waves/row (4096 blocks = 16b x 256 rows).
// Each wave: scores for 4 j-tiles (MFMA z^T) -> local (m,s,p) -> LDS; combiner wave merges.
__global__ __launch_bounds__(256) void k4ab(const float* __restrict__ P,
                                            const float* __restrict__ FCatt,
                                            const float* __restrict__ TCatt,
                                            float* __restrict__ FCgat,
                                            float* __restrict__ TCgat) {
    __shared__ float lds[4][36];          // per wave: [0]=m, [1]=s, [2..33]=p (unnormalized)
    int bi = blockIdx.x, tid = threadIdx.x;
    int w = tid >> 6, lane = tid & 63;
    int n = lane & 15, g = lane >> 4, kc = g * 8;
    const float* h; const float* G; float* out;
    int i, jt0, nparts, slot0;
    if (bi < 1024) {                      // FC
        int b = bi >> 6, rp = bi & 63;
        i = rp * 2 + (w >> 1); jt0 = (w & 1) * 4; nparts = 2; slot0 = (w >> 1) * 2;
        h = FCatt + (size_t)b * 4096; G = P + P_FC; out = FCgat + (size_t)b * 4096;
    } else {                              // TC
        int u = bi - 1024; int b = u >> 8;
        i = u & 255; jt0 = w * 4; nparts = 4; slot0 = 0;
        h = TCatt + (size_t)b * 8192; G = P + P_TCG; out = TCgat + (size_t)b * 8192;
    }

    union { u32 u4[4]; bf16x8 v; } B0, B1;
    #pragma unroll
    for (int e = 0; e < 4; e++) {
        B0.u4[e] = cvt_pk_bf16(G[G_APW + n * 32 + kc + 2 * e],
                               G[G_APW + n * 32 + kc + 2 * e + 1]);
        B1.u4[e] = cvt_pk_bf16(G[G_APW + (n + 16) * 32 + kc + 2 * e],
                               G[G_APW + (n + 16) * 32 + kc + 2 * e + 1]);
    }
    float awv0[4], awv1[4], abv0[4], abv1[4];
    #pragma unroll
    for (int r = 0; r < 4; r++) {
        awv0[r] = G[G_AW + g * 4 + r];
        awv1[r] = G[G_AW + 16 + g * 4 + r];
        abv0[r] = G[G_APB + g * 4 + r];
        abv1[r] = G[G_APB + 16 + g * 4 + r];
    }
    float hi[8];
    {
        const float4* hip = (const float4*)(h + (size_t)i * 32 + kc);
        float4 v0 = hip[0], v1 = hip[1];
        hi[0] = v0.x; hi[1] = v0.y; hi[2] = v0.z; hi[3] = v0.w;
        hi[4] = v1.x; hi[5] = v1.y; hi[6] = v1.z; hi[7] = v1.w;
    }
    // scores for this wave's 4 j-tiles
    float sc[4];
    #pragma unroll
    for (int q = 0; q < 4; q++) {
        int jt = jt0 + q;
        const float4* hjp = (const float4*)(h + ((size_t)jt * 16 + n) * 32 + kc);
        float4 v0 = hjp[0], v1 = hjp[1];
        union { u32 u4[4]; bf16x8 v; } A;
        A.u4[0] = cvt_pk_bf16(hi[0] * v0.x, hi[1] * v0.y);
        A.u4[1] = cvt_pk_bf16(hi[2] * v0.z, hi[3] * v0.w);
        A.u4[2] = cvt_pk_bf16(hi[4] * v1.x, hi[5] * v1.y);
        A.u4[3] = cvt_pk_bf16(hi[6] * v1.z, hi[7] * v1.w);
        f32x4 c0 = {0.f, 0.f, 0.f, 0.f}, c1 = {0.f, 0.f, 0.f, 0.f};
        c0 = __builtin_amdgcn_mfma_f32_16x16x32_bf16(B0.v, A.v, c0, 0, 0, 0);
        c1 = __builtin_amdgcn_mfma_f32_16x16x32_bf16(B1.v, A.v, c1, 0, 0, 0);
        float part = 0.f;
        #pragma unroll
        for (int r = 0; r < 4; r++) {
            part = fmaf(awv0[r], tanh_fast(c0[r] + abv0[r]), part);
            part = fmaf(awv1[r], tanh_fast(c1[r] + abv1[r]), part);
        }
        part += __shfl_xor(part, 16, 64);
        part += __shfl_xor(part, 32, 64);
        sc[q] = part;
    }
    // local max + sum over this wave's 64 j's
    float mh = fmaxf(fmaxf(sc[0], sc[1]), fmaxf(sc[2], sc[3]));
    #pragma unroll
    for (int off = 1; off < 16; off <<= 1) mh = fmaxf(mh, __shfl_xor(mh, off, 64));
    float sumh = 0.f;
    #pragma unroll
    for (int q = 0; q < 4; q++) { sc[q] = __expf(sc[q] - mh); sumh += sc[q]; }
    #pragma unroll
    for (int off = 1; off < 16; off <<= 1) sumh += __shfl_xor(sumh, off, 64);
    // PV partial (unnormalized)
    float attp[8] = {0.f, 0.f, 0.f, 0.f, 0.f, 0.f, 0.f, 0.f};
    #pragma unroll
    for (int q = 0; q < 4; q++) {
        int jt = jt0 + q;
        const float4* hjp = (const float4*)(h + ((size_t)jt * 16 + n) * 32 + kc);
        float4 v0 = hjp[0], v1 = hjp[1];
        float p = sc[q];
        attp[0] = fmaf(p, v0.x, attp[0]); attp[1] = fmaf(p, v0.y, attp[1]);
        attp[2] = fmaf(p, v0.z, attp[2]); attp[3] = fmaf(p, v0.w, attp[3]);
        attp[4] = fmaf(p, v1.x, attp[4]); attp[5] = fmaf(p, v1.y, attp[5]);
        attp[6] = fmaf(p, v1.z, attp[6]); attp[7] = fmaf(p, v1.w, attp[7]);
    }
    #pragma unroll
    for (int off = 1; off < 16; off <<= 1) {
        #pragma unroll
        for (int e = 0; e < 8; e++) attp[e] += __shfl_xor(attp[e], off, 64);
    }
    // publish partial state
    if (n == 0) {
        #pragma unroll
        for (int e = 0; e < 8; e++) lds[w][2 + g * 8 + e] = attp[e];
    }
    if (lane == 0) { lds[w][0] = mh; lds[w][1] = sumh; }
    __syncthreads();
    // combiner wave finishes the row
    bool comb = (nparts == 4) ? (w == 0) : ((w & 1) == 0);
    if (comb) {
        float hif[32];
        #pragma unroll
        for (int gg = 0; gg < 4; gg++) {
            #pragma unroll
            for (int e = 0; e < 8; e++) hif[gg * 8 + e] = __shfl(hi[e], gg << 4, 64);
        }
        int d = lane & 31;
        float z = G[G_PWB + d] + G[G_POB + d];
        if (nparts == 2) {
            float m0 = lds[slot0][0],     s0 = lds[slot0][1];
            float m1 = lds[slot0 + 1][0], s1 = lds[slot0 + 1][1];
            float Mx = fmaxf(m0, m1);
            float e0 = __expf(m0 - Mx), e1 = __expf(m1 - Mx);
            float inv = 1.f / (s0 * e0 + s1 * e1);
            #pragma unroll
            for (int c = 0; c < 32; c++) {
                float att = (lds[slot0][2 + c] * e0 + lds[slot0 + 1][2 + c] * e1) * inv;
                z = fmaf(G[G_PWW + d * 32 + c], att, fmaf(G[G_POW + d * 32 + c], hif[c], z));
            }
        } else {
            float m0 = lds[0][0], m1 = lds[1][0], m2 = lds[2][0], m3 = lds[3][0];
            float Mx = fmaxf(fmaxf(m0, m1), fmaxf(m2, m3));
            float e0 = __expf(m0 - Mx), e1 = __expf(m1 - Mx);
            float e2 = __expf(m2 - Mx), e3 = __expf(m3 - Mx);
            float inv = 1.f / (lds[0][1] * e0 + lds[1][1] * e1 +
                               lds[2][1] * e2 + lds[3][1] * e3);
            #pragma unroll
            for (int c = 0; c < 32; c++) {
                float att = (lds[0][2 + c] * e0 + lds[1][2 + c] * e1 +
                             lds[2][2 + c] * e2 + lds[3][2 + c] * e3) * inv;
                z = fmaf(G[G_PWW + d * 32 + c], att, fmaf(G[G_POW + d * 32 + c], hif[c], z));
            }
        }
        z = z * G[G_GS + d] + G[G_GB + d];
        z = SELU_L * ((z > 0.f) ? z : SELU_A * (__expf(z) - 1.f));
        if (lane < 32) out[(size_t)i * 32 + d] = z;
    }
}

// ---------------- K5: top-k pooling (rank-select) ----------------
__global__ __launch_bounds__(256) void k5_pool(const float* __restrict__ P,
                                               const float* __restrict__ FCgat,
                                               const float* __restrict__ TCgat,
                                               float* __restrict__ XF,
                                               float* __restrict__ XT) {
    __shared__ float s[256];
    int bi = blockIdx.x;
    int N, kn, b, pboff; const float* g; float* xp; const float* pw;
    if (bi < 16) { b = bi; N = 128; kn = 64;
        g = FCgat + (size_t)b * 4096; xp = XF + (size_t)b * 2048; pw = P + P_PFW; pboff = P_PFB; }
    else { b = bi - 16; N = 256; kn = 128;
        g = TCgat + (size_t)b * 8192; xp = XT + (size_t)b * 4096; pw = P + P_PTW; pboff = P_PTB; }
    int tid = threadIdx.x;
    float sv = 0.f;
    if (tid < N) {
        float z = P[pboff];
        #pragma unroll
        for (int d = 0; d < 32; d++) z = fmaf(pw[d], g[(size_t)tid * 32 + d], z);
        sv = 1.f / (1.f + __expf(-z));
        s[tid] = sv;
    }
    __syncthreads();
    if (tid < N) {
        int rank = 0;
        for (int l = 0; l < N; l++) {
            float sl = s[l];
            rank += (sl > sv) || (sl == sv && l < tid);
        }
        if (rank < kn) {
            #pragma unroll
            for (int d = 0; d < 32; d++) xp[(size_t)rank * 32 + d] = g[(size_t)tid * 32 + d] * sv;
        }
    }
}

// ---------------- K6: cross fusion (wave per output row) ----------------
__global__ __launch_bounds__(256) void k6_fuse(const float* __restrict__ P,
                                               const float* __restrict__ XF,
                                               const float* __restrict__ XT,
                                               float* __restrict__ XFF,
                                               float* __restrict__ XTF) {
    int wid = blockIdx.x * 4 + (threadIdx.x >> 6);
    int lane = threadIdx.x & 63;
    if (wid < 1024) {
        int b = wid >> 6, i = wid & 63;
        const float* xf  = XF + ((size_t)b * 64 + i) * 32;
        const float* xtb = XT + (size_t)b * 4096;
        const float* w1 = P + P_W1;
        int d = lane & 31;
        float y = 0.f;
        #pragma unroll
        for (int c = 0; c < 32; c++) y = fmaf(w1[d * 32 + c], xf[c], y);
        float xtr0[32], xtr1[32];
        #pragma unroll
        for (int c = 0; c < 32; c++) {
            xtr0[c] = xtb[(size_t)lane * 32 + c];
            xtr1[c] = xtb[(size_t)(lane + 64) * 32 + c];
        }
        float s0 = 0.f, s1 = 0.f;
        #pragma unroll
        for (int c = 0; c < 32; c++) {
            float yc = __shfl(y, c, 64);
            s0 = fmaf(yc, xtr0[c], s0);
            s1 = fmaf(yc, xtr1[c], s1);
        }
        float mx = fmaxf(s0, s1);
        #pragma unroll
        for (int off = 1; off < 64; off <<= 1) mx = fmaxf(mx, __shfl_xor(mx, off, 64));
        float e0 = __expf(s0 - mx), e1 = __expf(s1 - mx);
        float sm = e0 + e1;
        #pragma unroll
        for (int off = 1; off < 64; off <<= 1) sm += __shfl_xor(sm, off, 64);
        float inv = 1.f / sm;
        float a0 = e0 * inv, a1 = e1 * inv;
        float v[32];
        #pragma unroll
        for (int c = 0; c < 32; c++) v[c] = a0 * xtr0[c] + a1 * xtr1[c];
        #pragma unroll
        for (int off = 1; off < 64; off <<= 1) {
            #pragma unroll
            for (int c = 0; c < 32; c++) v[c] += __shfl_xor(v[c], off, 64);
        }
        if (lane == 0) {
            float* o = XFF + ((size_t)b * 64 + i) * 32;
            #pragma unroll
            for (int c = 0; c < 32; c++) o[c] = xf[c] + v[c];
        }
    } else {
        int r = wid - 1024;
        int b = r >> 7, i = r & 127;
        const float* xt  = XT + ((size_t)b * 128 + i) * 32;
        const float* xfb = XF + (size_t)b * 2048;
        const float* w2 = P + P_W2;
        int d = lane & 31;
        float y = 0.f;
        #pragma unroll
        for (int c = 0; c < 32; c++) y = fmaf(w2[d * 32 + c], xt[c], y);
        float xfr[32];
        #pragma unroll
        for (int c = 0; c < 32; c++) xfr[c] = xfb[(size_t)lane * 32 + c];
        float sc0 = 0.f;
        #pragma unroll
        for (int c = 0; c < 32; c++) sc0 = fmaf(__shfl(y, c, 64), xfr[c], sc0);
        float mx = sc0;
        #pragma unroll
        for (int off = 1; off < 64; off <<= 1) mx = fmaxf(mx, __shfl_xor(mx, off, 64));
        float e = __expf(sc0 - mx);
        float sm = e;
        #pragma unroll
        for (int off = 1; off < 64; off <<= 1) sm += __shfl_xor(sm, off, 64);
        float a = e / sm;
        float v[32];
        #pragma unroll
        for (int c = 0; c < 32; c++) v[c] = a * xfr[c];
        #pragma unroll
        for (int off = 1; off < 64; off <<= 1) {
            #pragma unroll
            for (int c = 0; c < 32; c++) v[c] += __shfl_xor(v[c], off, 64);
        }
        if (lane == 0) {
            float* o = XTF + ((size_t)b * 128 + i) * 32;
            #pragma unroll
            for (int c = 0; c < 32; c++) o[c] = xt[c] + v[c];
        }
    }
}

// ---------------- K7: row-max + final FC (dtype-aware output) ----------------
__global__ __launch_bounds__(64) void k7_out(const float* __restrict__ P,
                                             const float* __restrict__ XFF,
                                             const float* __restrict__ XTF,
                                             void* __restrict__ outp) {
    __shared__ float node[64];
    int b = blockIdx.x, tid = threadIdx.x;
    if (tid < 32) {
        float m = -1e30f;
        for (int r = 0; r < 64; r++) m = fmaxf(m, XFF[((size_t)b * 64 + r) * 32 + tid]);
        node[tid] = m;
    } else {
        int c = tid - 32;
        float m = -1e30f;
        for (int r = 0; r < 128; r++) m = fmaxf(m, XTF[((size_t)b * 128 + r) * 32 + c]);
        node[tid] = m;
    }
    __syncthreads();
    if (tid < 2) {
        float z = P[P_FCB + tid];
        #pragma unroll
        for (int k = 0; k < 64; k++) z = fmaf(P[P_FCW + tid * 64 + k], node[k], z);
        int isb = (int)P[P_FLAG];
        if (isb) ((u16*)outp)[b * 2 + tid] = f2bf(z);
        else     ((float*)outp)[b * 2 + tid] = z;
    }
}

// ---------------- launch ----------------
extern "C" void kernel_launch(void* const* d_in, const int* in_sizes, int n_in,
                              void* d_out, int out_size, void* d_ws, size_t ws_size,
                              hipStream_t stream) {
    (void)in_sizes; (void)n_in; (void)out_size; (void)ws_size;
    float* W = (float*)d_ws;
    Ptrs ptrs;
    for (int i = 0; i < 39; i++) ptrs.p[i] = d_in[i];
    const void* x = d_in[0];
    float* P = W;

    k0_setup<<<4, 256, 0, stream>>>(ptrs, P);
    k1_conv_m<<<2048, 256, 0, stream>>>(x, P, W + WS_M);
    k2_softmax<<<128, 256, 0, stream>>>(W + WS_M, W + WS_FCATT);
    k3n<<<512, 256, 0, stream>>>(x, W + WS_M, P, W + WS_FCATT, W + WS_TCATT);
    k4ab<<<5120, 256, 0, stream>>>(P, W + WS_FCATT, W + WS_TCATT,
                                   W + WS_FCGAT, W + WS_TCGAT);
    k5_pool<<<32, 256, 0, stream>>>(P, W + WS_FCGAT, W + WS_TCGAT, W + WS_XF, W + WS_XT);
    k6_fuse<<<768, 256, 0, stream>>>(P, W + WS_XF, W + WS_XT, W + WS_XFF, W + WS_XTF);
    k7_out<<<16, 64, 0, stream>>>(P, W + WS_XFF, W + WS_XTF, d_out);
}

// Round 12
// 306.275 us; speedup vs baseline: 1.0259x; 1.0259x over previous
//
#include <hip/hip_runtime.h>
#include <hip/hip_bf16.h>

// ---------------- problem constants ----------------
#define Bn 16
#define Tn 256
#define Fn 128
#define Cn 32
#define Dn 32
#define EPSf 1e-5f
#define SELU_L 1.0507009873554805f
#define SELU_A 1.6732632423543772f

typedef unsigned short u16;
typedef unsigned int u32;
typedef __attribute__((ext_vector_type(8))) short bf16x8;
typedef __attribute__((ext_vector_type(4))) float f32x4;

struct Ptrs { const void* p[39]; };

// ---------------- param offsets (floats, in ws) ----------------
#define P_C1W 0          // 1024
#define P_C1B 1024       // 32
#define P_MW  1056       // 32  (= c2w*bnA*selu_lambda)
#define P_MK  1088       // 1
#define P_FC  1089       // gat block, 3264 floats
#define P_TCG (1089+3264)
// gat block internal
#define G_APW 0
#define G_APB 1024
#define G_AW  1056
#define G_PWW 1088
#define G_PWB 2112
#define G_POW 2144
#define G_POB 3168
#define G_GS  3200
#define G_GB  3232
#define GAT_SZ 3264
#define P_PFW (P_TCG+GAT_SZ)   // 32
#define P_PFB (P_PFW+32)       // 1
#define P_PTW (P_PFB+1)        // 32
#define P_PTB (P_PTW+32)       // 1
#define P_W1  (P_PTB+1)        // 1024
#define P_W2  (P_W1+1024)      // 1024
#define P_FCW (P_W2+1024)      // 128
#define P_FCB (P_FCW+128)      // 2
#define P_FLAG 10000           // 1.0 if inputs are bf16, 0.0 if fp32

// ---------------- ws layout (floats) ----------------
#define WS_M     10240                    // 524288
#define WS_FCATT (WS_M+524288)            // 65536   (B,128,32)
#define WS_TCATT (WS_FCATT+65536)         // 131072  (B,256,32)
#define WS_FCGAT (WS_TCATT+131072)        // 65536
#define WS_TCGAT (WS_FCGAT+65536)         // 131072
#define WS_XF    (WS_TCGAT+131072)        // 32768   (B,64,32)
#define WS_XT    (WS_XF+32768)            // 65536   (B,128,32)
#define WS_XFF   (WS_XT+65536)            // 32768
#define WS_XTF   (WS_XFF+32768)           // 65536

// ---------------- helpers ----------------
__device__ __forceinline__ float bf2f(u16 u) {
    union { u32 i; float f; } v; v.i = ((u32)u) << 16; return v.f;
}
__device__ __forceinline__ u16 f2bf(float f) {
    union { float f; u32 u; } v; v.f = f;
    u32 r = (v.u + 0x7fffu + ((v.u >> 16) & 1u)) >> 16;
    return (u16)r;
}
__device__ __forceinline__ u32 cvt_pk_bf16(float lo, float hi) {
    u32 r;
    asm("v_cvt_pk_bf16_f32 %0, %1, %2" : "=v"(r) : "v"(lo), "v"(hi));
    return r;
}
__device__ __forceinline__ void up2(u32 u, float* o) {
    union { u32 i; float f; } a, b;
    a.i = u << 16; b.i = u & 0xffff0000u;
    o[0] = a.f; o[1] = b.f;
}
__device__ __forceinline__ float tanh_fast(float x) {
    float e = __expf(2.f * x);
    return 1.f - 2.f / (e + 1.f);
}
__device__ __forceinline__ float ldp(const void* p, int i, int isb) {
    return isb ? bf2f(((const u16*)p)[i]) : ((const float*)p)[i];
}

// ---------------- K0: detect dtype + convert/fold params (parallel, 4 blocks) ----------------
__global__ __launch_bounds__(256) void k0_setup(Ptrs in, float* __restrict__ P) {
    __shared__ int sflag;
    int tid = threadIdx.x;
    int blk = blockIdx.x;
    if (tid < 64) {
        const u16* xu = (const u16*)in.p[0];
        int bad = 0;
        #pragma unroll
        for (int q = 0; q < 4; q++) {
            float f = bf2f(xu[tid * 4 + q]);
            float a = fabsf(f);
            if (!(a < 64.f) && !(a == 0.f)) bad++;
        }
        #pragma unroll
        for (int off = 32; off >= 1; off >>= 1) bad += __shfl_xor(bad, off, 64);
        if (tid == 0) sflag = (bad <= 8) ? 1 : 0;
    }
    __syncthreads();
    const int isb = sflag;

    if (blk == 0) {
        if (tid == 0) P[P_FLAG] = (float)isb;
        for (int i = tid; i < 1024; i += 256) P[P_C1W + i] = ldp(in.p[1], i, isb);
        if (tid < 32) {
            float A = ldp(in.p[3], tid, isb) * rsqrtf(ldp(in.p[6], tid, isb) + EPSf);
            float w = ldp(in.p[7], tid, isb);
            P[P_C1B + tid] = ldp(in.p[2], tid, isb);
            P[P_MW + tid] = w * A * SELU_L;
            float Bc = ldp(in.p[4], tid, isb) - ldp(in.p[5], tid, isb) * A;
            float term = w * Bc;
            #pragma unroll
            for (int off = 16; off >= 1; off >>= 1) term += __shfl_xor(term, off, 64);
            if (tid == 0) P[P_MK] = term + ldp(in.p[8], 0, isb);
        }
        if (tid >= 64 && tid < 96) {
            int t = tid - 64;
            P[P_PFW + t] = ldp(in.p[31], t, isb);
            P[P_PTW + t] = ldp(in.p[33], t, isb);
        }
        if (tid == 96) { P[P_PFB] = ldp(in.p[32], 0, isb); P[P_PTB] = ldp(in.p[34], 0, isb); }
        if (tid == 97) P[P_FCB]     = ldp(in.p[38], 0, isb);
        if (tid == 98) P[P_FCB + 1] = ldp(in.p[38], 1, isb);
        if (tid >= 128) P[P_FCW + (tid - 128)] = ldp(in.p[37], tid - 128, isb);
    } else if (blk <= 2) {
        int g = blk - 1;
        int ib = g ? 20 : 9;
        float* G = P + (g ? P_TCG : P_FC);
        for (int i = tid; i < 1024; i += 256) {
            G[G_APW + i] = ldp(in.p[ib + 0], i, isb);
            G[G_PWW + i] = ldp(in.p[ib + 3], i, isb);
            G[G_POW + i] = ldp(in.p[ib + 5], i, isb);
        }
        if (tid < 32) {
            G[G_APB + tid] = ldp(in.p[ib + 1], tid, isb);
            G[G_AW  + tid] = ldp(in.p[ib + 2], tid, isb);
            G[G_PWB + tid] = ldp(in.p[ib + 4], tid, isb);
            G[G_POB + tid] = ldp(in.p[ib + 6], tid, isb);
            float gs = ldp(in.p[ib + 7], tid, isb) * rsqrtf(ldp(in.p[ib + 10], tid, isb) + EPSf);
            G[G_GS + tid] = gs;
            G[G_GB + tid] = ldp(in.p[ib + 8], tid, isb) - ldp(in.p[ib + 9], tid, isb) * gs;
        }
    } else {
        for (int i = tid; i < 1024; i += 256) {
            P[P_W1 + i] = ldp(in.p[35], i, isb);
            P[P_W2 + i] = ldp(in.p[36], i, isb);
        }
    }
}

// ---------------- K1: conv1 + SELU + BN + conv2 -> m (MFMA, transposed epilogue) ----------------
__global__ __launch_bounds__(256) void k1_conv_m(const void* __restrict__ xin,
                                                 const float* __restrict__ P,
                                                 float* __restrict__ M) {
    const int isb = __builtin_amdgcn_readfirstlane((int)P[P_FLAG]);
    int tid = threadIdx.x;
    if (isb) {
        int w = tid >> 6, lane = tid & 63;
        int n = lane & 15, g = lane >> 4, kc = g * 8;
        union { u32 u[4]; bf16x8 v; } B0, B1;
        #pragma unroll
        for (int e = 0; e < 4; e++) {
            B0.u[e] = cvt_pk_bf16(P[P_C1W + n * 32 + kc + 2 * e],
                                  P[P_C1W + n * 32 + kc + 2 * e + 1]);
            B1.u[e] = cvt_pk_bf16(P[P_C1W + (n + 16) * 32 + kc + 2 * e],
                                  P[P_C1W + (n + 16) * 32 + kc + 2 * e + 1]);
        }
        float cb0v[4], cb1v[4], mw0v[4], mw1v[4];
        #pragma unroll
        for (int r = 0; r < 4; r++) {
            cb0v[r] = P[P_C1B + g * 4 + r];
            cb1v[r] = P[P_C1B + 16 + g * 4 + r];
            mw0v[r] = P[P_MW + g * 4 + r];
            mw1v[r] = P[P_MW + 16 + g * 4 + r];
        }
        float mk = P[P_MK];
        int rowblk = blockIdx.x * 256 + w * 64;
        const u16* xp = (const u16*)xin + (size_t)rowblk * 32;
        bf16x8 a[4];
        #pragma unroll
        for (int s = 0; s < 4; s++)
            a[s] = *(const bf16x8*)(xp + ((size_t)s * 16 + n) * 32 + kc);
        #pragma unroll
        for (int s = 0; s < 4; s++) {
            f32x4 c0 = {0.f, 0.f, 0.f, 0.f}, c1 = {0.f, 0.f, 0.f, 0.f};
            c0 = __builtin_amdgcn_mfma_f32_16x16x32_bf16(B0.v, a[s], c0, 0, 0, 0);
            c1 = __builtin_amdgcn_mfma_f32_16x16x32_bf16(B1.v, a[s], c1, 0, 0, 0);
            float part = 0.f;
            #pragma unroll
            for (int r = 0; r < 4; r++) {
                float z0 = c0[r] + cb0v[r], z1 = c1[r] + cb1v[r];
                float s0 = (z0 > 0.f) ? z0 : SELU_A * (__expf(z0) - 1.f);
                float s1 = (z1 > 0.f) ? z1 : SELU_A * (__expf(z1) - 1.f);
                part = fmaf(mw0v[r], s0, part);
                part = fmaf(mw1v[r], s1, part);
            }
            part += __shfl_xor(part, 16, 64);
            part += __shfl_xor(part, 32, 64);
            if (lane < 16) M[(size_t)rowblk + s * 16 + n] = part + mk;
        }
    } else {
        int idx = blockIdx.x * 256 + tid;
        float xv[32];
        const float4* xf4 = reinterpret_cast<const float4*>((const float*)xin + (size_t)idx * 32);
        #pragma unroll
        for (int q = 0; q < 8; q++) {
            float4 v = xf4[q];
            xv[q * 4 + 0] = v.x; xv[q * 4 + 1] = v.y;
            xv[q * 4 + 2] = v.z; xv[q * 4 + 3] = v.w;
        }
        float acc = P[P_MK];
        #pragma unroll
        for (int o = 0; o < 32; o++) {
            float z = P[P_C1B + o];
            #pragma unroll
            for (int c = 0; c < 32; c++) z = fmaf(P[P_C1W + o * 32 + c], xv[c], z);
            float br = (z > 0.f) ? z : SELU_A * (__expf(z) - 1.f);
            acc = fmaf(P[P_MW + o], br, acc);
        }
        M[idx] = acc;
    }
}

// ---------------- K2: softmax over T + zero FCatt (128 blocks, float4, 3 barriers) ----------------
__global__ __launch_bounds__(256) void k2_softmax(float* __restrict__ M,
                                                  float* __restrict__ FCzero) {
    __shared__ float wred[4][16];
    int b = blockIdx.x >> 3, fg = blockIdx.x & 7;
    int tid = threadIdx.x;
    int w = tid >> 6, lane = tid & 63;
    int fq = tid & 3, tt = tid >> 2;
    float* colb = M + (size_t)b * (Tn * Fn) + fg * 16 + fq * 4;
    float4 v[4];
    float mx[4] = {-1e30f, -1e30f, -1e30f, -1e30f};
    #pragma unroll
    for (int p = 0; p < 4; p++) {
        v[p] = *(float4*)(colb + (size_t)(tt + p * 64) * Fn);
        mx[0] = fmaxf(mx[0], v[p].x); mx[1] = fmaxf(mx[1], v[p].y);
        mx[2] = fmaxf(mx[2], v[p].z); mx[3] = fmaxf(mx[3], v[p].w);
    }
    #pragma unroll
    for (int off = 4; off <= 32; off <<= 1) {
        #pragma unroll
        for (int c = 0; c < 4; c++) mx[c] = fmaxf(mx[c], __shfl_xor(mx[c], off, 64));
    }
    if (lane < 4) {
        #pragma unroll
        for (int c = 0; c < 4; c++) wred[w][lane * 4 + c] = mx[c];
    }
    __syncthreads();
    #pragma unroll
    for (int c = 0; c < 4; c++)
        mx[c] = fmaxf(fmaxf(wred[0][fq * 4 + c], wred[1][fq * 4 + c]),
                      fmaxf(wred[2][fq * 4 + c], wred[3][fq * 4 + c]));
    float4 e[4];
    float sm[4] = {0.f, 0.f, 0.f, 0.f};
    #pragma unroll
    for (int p = 0; p < 4; p++) {
        e[p].x = __expf(v[p].x - mx[0]); sm[0] += e[p].x;
        e[p].y = __expf(v[p].y - mx[1]); sm[1] += e[p].y;
        e[p].z = __expf(v[p].z - mx[2]); sm[2] += e[p].z;
        e[p].w = __expf(v[p].w - mx[3]); sm[3] += e[p].w;
    }
    #pragma unroll
    for (int off = 4; off <= 32; off <<= 1) {
        #pragma unroll
        for (int c = 0; c < 4; c++) sm[c] += __shfl_xor(sm[c], off, 64);
    }
    __syncthreads();
    if (lane < 4) {
        #pragma unroll
        for (int c = 0; c < 4; c++) wred[w][lane * 4 + c] = sm[c];
    }
    __syncthreads();
    float inv[4];
    #pragma unroll
    for (int c = 0; c < 4; c++)
        inv[c] = 1.f / (wred[0][fq * 4 + c] + wred[1][fq * 4 + c] +
                        wred[2][fq * 4 + c] + wred[3][fq * 4 + c]);
    #pragma unroll
    for (int p = 0; p < 4; p++) {
        float4 o4 = make_float4(e[p].x * inv[0], e[p].y * inv[1],
                                e[p].z * inv[2], e[p].w * inv[3]);
        *(float4*)(colb + (size_t)(tt + p * 64) * Fn) = o4;
    }
    int gid = blockIdx.x * 256 + tid;
    for (int i = gid; i < Bn * Fn * Cn; i += 128 * 256) FCzero[i] = 0.f;
}

// ---------------- K3: FCatt + TCatt — 16B loads, LDS transpose, contiguous atomics ----------------
__global__ __launch_bounds__(256) void k3n(const void* __restrict__ xin,
                                           const float* __restrict__ M,
                                           const float* __restrict__ Pflag,
                                           float* __restrict__ FCatt,
                                           float* __restrict__ TCatt) {
    __shared__ float part[4][8][32];     // [wave][tt][c]
    __shared__ __align__(16) float sh[4096];
    int bi = blockIdx.x;                 // 512 blocks: b*32 + tg (8 t's each)
    int b = bi >> 5, tg = bi & 31;
    int tid = threadIdx.x;
    int w = tid >> 6, lane = tid & 63;
    int cc = (tid & 3) * 8, f0 = tid >> 2;
    const int isb = __builtin_amdgcn_readfirstlane((int)Pflag[P_FLAG]);
    float fa0[8], fa1[8];
    #pragma unroll
    for (int e = 0; e < 8; e++) { fa0[e] = 0.f; fa1[e] = 0.f; }
    for (int tt = 0; tt < 8; tt++) {
        int t = tg * 8 + tt;
        const float* Mrow = M + (size_t)b * (Tn * Fn) + (size_t)t * Fn;
        float m0 = Mrow[f0], m1 = Mrow[f0 + 64];
        size_t rowoff = ((size_t)b * Tn + t) * (Fn * Cn);
        float xv0[8], xv1[8];
        if (isb) {
            const u16* xr = (const u16*)xin + rowoff + f0 * 32 + cc;
            union { u32 u[4]; bf16x8 v; } q0, q1;
            q0.v = *(const bf16x8*)xr;
            q1.v = *(const bf16x8*)(xr + 64 * 32);
            up2(q0.u[0], xv0 + 0); up2(q0.u[1], xv0 + 2);
            up2(q0.u[2], xv0 + 4); up2(q0.u[3], xv0 + 6);
            up2(q1.u[0], xv1 + 0); up2(q1.u[1], xv1 + 2);
            up2(q1.u[2], xv1 + 4); up2(q1.u[3], xv1 + 6);
        } else {
            const float* xr = (const float*)xin + rowoff + f0 * 32 + cc;
            float4 a0 = *(const float4*)xr, a1 = *(const float4*)(xr + 4);
            float4 b0 = *(const float4*)(xr + 64 * 32), b1 = *(const float4*)(xr + 64 * 32 + 4);
            xv0[0] = a0.x; xv0[1] = a0.y; xv0[2] = a0.z; xv0[3] = a0.w;
            xv0[4] = a1.x; xv0[5] = a1.y; xv0[6] = a1.z; xv0[7] = a1.w;
            xv1[0] = b0.x; xv1[1] = b0.y; xv1[2] = b0.z; xv1[3] = b0.w;
            xv1[4] = b1.x; xv1[5] = b1.y; xv1[6] = b1.z; xv1[7] = b1.w;
        }
        float tp[8];
        #pragma unroll
        for (int e = 0; e < 8; e++) {
            float p0 = xv0[e] * m0, p1 = xv1[e] * m1;
            fa0[e] += p0; fa1[e] += p1;
            tp[e] = p0 + p1;
        }
        #pragma unroll
        for (int off = 4; off <= 32; off <<= 1) {
            #pragma unroll
            for (int e = 0; e < 8; e++) tp[e] += __shfl_xor(tp[e], off, 64);
        }
        if (lane < 4) {
            #pragma unroll
            for (int e = 0; e < 8; e++) part[w][tt][lane * 8 + e] = tp[e];
        }
    }
    // stage FCatt partials to LDS, thread-linear (fa0[e] belongs at 8*tid+e; fa1 at +2048)
    float4* sh4 = (float4*)sh;
    sh4[tid * 2]       = make_float4(fa0[0], fa0[1], fa0[2], fa0[3]);
    sh4[tid * 2 + 1]   = make_float4(fa0[4], fa0[5], fa0[6], fa0[7]);
    sh4[512 + tid * 2]     = make_float4(fa1[0], fa1[1], fa1[2], fa1[3]);
    sh4[512 + tid * 2 + 1] = make_float4(fa1[4], fa1[5], fa1[6], fa1[7]);
    __syncthreads();
    {
        int tt = tid >> 5, c = tid & 31;
        float s = part[0][tt][c] + part[1][tt][c] + part[2][tt][c] + part[3][tt][c];
        TCatt[((size_t)b * Tn + tg * 8 + tt) * Cn + c] = s;
    }
    // contiguous atomics (round-5 layout): wave-instr covers 128 consecutive floats
    #pragma unroll
    for (int k = 0; k < 8; k++) {
        float2 v = *(float2*)&sh[tid * 2 + 512 * k];
        atomicAdd(&FCatt[(size_t)b * 4096 + tid * 2 + 512 * k],     v.x);
        atomicAdd(&FCatt[(size_t)b * 4096 + tid * 2 + 512 * k + 1], v.y);
    }
}

// ---------------- K4ab: fused GAT (round-10 shape: 8 j-tiles per wave) ----------------
// FC: 1 wave per row (8 j-tiles, self-contained).
// TC: 2 waves per row (8 j-tiles each) + LDS two-partial softmax combine.
template<int NT>
__device__ __forceinline__ void gat_row(const float* __restrict__ h,
                                        const float* __restrict__ G,
                                        float* __restrict__ out,
                                        int i, int lane) {
    int n = lane & 15, g = lane >> 4, kc = g * 8;
    union { u32 u[4]; bf16x8 v; } B0, B1;
    #pragma unroll
    for (int e = 0; e < 4; e++) {
        B0.u[e] = cvt_pk_bf16(G[G_APW + n * 32 + kc + 2 * e],
                              G[G_APW + n * 32 + kc + 2 * e + 1]);
        B1.u[e] = cvt_pk_bf16(G[G_APW + (n + 16) * 32 + kc + 2 * e],
                              G[G_APW + (n + 16) * 32 + kc + 2 * e + 1]);
    }
    float awv0[4], awv1[4], abv0[4], abv1[4];
    #pragma unroll
    for (int r = 0; r < 4; r++) {
        awv0[r] = G[G_AW + g * 4 + r];
        awv1[r] = G[G_AW + 16 + g * 4 + r];
        abv0[r] = G[G_APB + g * 4 + r];
        abv1[r] = G[G_APB + 16 + g * 4 + r];
    }
    float hi[8];
    {
        const float4* hip = (const float4*)(h + (size_t)i * 32 + kc);
        float4 v0 = hip[0], v1 = hip[1];
        hi[0] = v0.x; hi[1] = v0.y; hi[2] = v0.z; hi[3] = v0.w;
        hi[4] = v1.x; hi[5] = v1.y; hi[6] = v1.z; hi[7] = v1.w;
    }
    float sc[NT];
    #pragma unroll
    for (int jt = 0; jt < NT; jt++) {
        const float4* hjp = (const float4*)(h + ((size_t)jt * 16 + n) * 32 + kc);
        float4 v0 = hjp[0], v1 = hjp[1];
        union { u32 u[4]; bf16x8 v; } A;
        A.u[0] = cvt_pk_bf16(hi[0] * v0.x, hi[1] * v0.y);
        A.u[1] = cvt_pk_bf16(hi[2] * v0.z, hi[3] * v0.w);
        A.u[2] = cvt_pk_bf16(hi[4] * v1.x, hi[5] * v1.y);
        A.u[3] = cvt_pk_bf16(hi[6] * v1.z, hi[7] * v1.w);
        f32x4 c0 = {0.f, 0.f, 0.f, 0.f}, c1 = {0.f, 0.f, 0.f, 0.f};
        c0 = __builtin_amdgcn_mfma_f32_16x16x32_bf16(B0.v, A.v, c0, 0, 0, 0);
        c1 = __builtin_amdgcn_mfma_f32_16x16x32_bf16(B1.v, A.v, c1, 0, 0, 0);
        float part = 0.f;
        #pragma unroll
        for (int r = 0; r < 4; r++) {
            part = fmaf(awv0[r], tanh_fast(c0[r] + abv0[r]), part);
            part = fmaf(awv1[r], tanh_fast(c1[r] + abv1[r]), part);
        }
        part += __shfl_xor(part, 16, 64);
        part += __shfl_xor(part, 32, 64);
        sc[jt] = part;
    }
    float mx = -1e30f;
    #pragma unroll
    for (int jt = 0; jt < NT; jt++) mx = fmaxf(mx, sc[jt]);
    #pragma unroll
    for (int off = 1; off < 16; off <<= 1) mx = fmaxf(mx, __shfl_xor(mx, off, 64));
    float sum = 0.f;
    #pragma unroll
    for (int jt = 0; jt < NT; jt++) { sc[jt] = __expf(sc[jt] - mx); sum += sc[jt]; }
    #pragma unroll
    for (int off = 1; off < 16; off <<= 1) sum += __shfl_xor(sum, off, 64);
    float inv = 1.f / sum;
    float attp[8] = {0.f, 0.f, 0.f, 0.f, 0.f, 0.f, 0.f, 0.f};
    #pragma unroll
    for (int jt = 0; jt < NT; jt++) {
        const float4* hjp = (const float4*)(h + ((size_t)jt * 16 + n) * 32 + kc);
        float4 v0 = hjp[0], v1 = hjp[1];
        float p = sc[jt];
        attp[0] = fmaf(p, v0.x, attp[0]); attp[1] = fmaf(p, v0.y, attp[1]);
        attp[2] = fmaf(p, v0.z, attp[2]); attp[3] = fmaf(p, v0.w, attp[3]);
        attp[4] = fmaf(p, v1.x, attp[4]); attp[5] = fmaf(p, v1.y, attp[5]);
        attp[6] = fmaf(p, v1.z, attp[6]); attp[7] = fmaf(p, v1.w, attp[7]);
    }
    #pragma unroll
    for (int off = 1; off < 16; off <<= 1) {
        #pragma unroll
        for (int e = 0; e < 8; e++) attp[e] += __shfl_xor(attp[e], off, 64);
    }
    #pragma unroll
    for (int e = 0; e < 8; e++) attp[e] *= inv;
    float att[32], hif[32];
    #pragma unroll
    for (int gg = 0; gg < 4; gg++) {
        #pragma unroll
        for (int e = 0; e < 8; e++) {
            att[gg * 8 + e] = __shfl(attp[e], gg << 4, 64);
            hif[gg * 8 + e] = __shfl(hi[e],  gg << 4, 64);
        }
    }
    int d = lane & 31;
    float z = G[G_PWB + d] + G[G_POB + d];
    #pragma unroll
    for (int c = 0; c < 32; c++)
        z = fmaf(G[G_PWW + d * 32 + c], att[c], fmaf(G[G_POW + d * 32 + c], hif[c], z));
    z = z * G[G_GS + d] + G[G_GB + d];
    z = SELU_L * ((z > 0.f) ? z : SELU_A * (__expf(z) - 1.f));
    if (lane < 32) out[(size_t)i * 32 + d] = z;
}

__global__ __launch_bounds__(256) void k4ab(const float* __restrict__ P,
                                            const float* __restrict__ FCatt,
                                            const float* __restrict__ TCatt,
                                            float* __restrict__ FCgat,
                                            float* __restrict__ TCgat) {
    int bi = blockIdx.x, tid = threadIdx.x;
    int w = tid >> 6, lane = tid & 63;
    if (bi < 512) {                       // FC: 1 wave per row
        int b = bi >> 5, i = (bi & 31) * 4 + w;
        gat_row<8>(FCatt + (size_t)b * 4096, P + P_FC, FCgat + (size_t)b * 4096, i, lane);
        return;
    }
    // TC: 2 waves per row, LDS combine. 2048 blocks: b = u>>7, row-pair = u&127.
    __shared__ float lds[4][36];          // per wave: [0]=m, [1]=s, [2..33]=p (unnormalized)
    int u = bi - 512;
    int b = u >> 7;
    int rp = u & 127;
    int i = rp * 2 + (w >> 1);            // row for this wave
    int hf = w & 1;                       // j-half
    const float* h = TCatt + (size_t)b * 8192;
    const float* G = P + P_TCG;
    float* out = TCgat + (size_t)b * 8192;
    int n = lane & 15, g = lane >> 4, kc = g * 8;

    union { u32 u4[4]; bf16x8 v; } B0, B1;
    #pragma unroll
    for (int e = 0; e < 4; e++) {
        B0.u4[e] = cvt_pk_bf16(G[G_APW + n * 32 + kc + 2 * e],
                               G[G_APW + n * 32 + kc + 2 * e + 1]);
        B1.u4[e] = cvt_pk_bf16(G[G_APW + (n + 16) * 32 + kc + 2 * e],
                               G[G_APW + (n + 16) * 32 + kc + 2 * e + 1]);
    }
    float awv0[4], awv1[4], abv0[4], abv1[4];
    #pragma unroll
    for (int r = 0; r < 4; r++) {
        awv0[r] = G[G_AW + g * 4 + r];
        awv1[r] = G[G_AW + 16 + g * 4 + r];
        abv0[r] = G[G_APB + g * 4 + r];
        abv1[r] = G[G_APB + 16 + g * 4 + r];
    }
    float hi[8];
    {
        const float4* hip = (const float4*)(h + (size_t)i * 32 + kc);
        float4 v0 = hip[0], v1 = hip[1];
        hi[0] = v0.x; hi[1] = v0.y; hi[2] = v0.z; hi[3] = v0.w;
        hi[4] = v1.x; hi[5] = v1.y; hi[6] = v1.z; hi[7] = v1.w;
    }
    // scores for this half: jt = hf*8 + q
    float sc[8];
    #pragma unroll
    for (int q = 0; q < 8; q++) {
        int jt = hf * 8 + q;
        const float4* hjp = (const float4*)(h + ((size_t)jt * 16 + n) * 32 + kc);
        float4 v0 = hjp[0], v1 = hjp[1];
        union { u32 u4[4]; bf16x8 v; } A;
        A.u4[0] = cvt_pk_bf16(hi[0] * v0.x, hi[1] * v0.y);
        A.u4[1] = cvt_pk_bf16(hi[2] * v0.z, hi[3] * v0.w);
        A.u4[2] = cvt_pk_bf16(hi[4] * v1.x, hi[5] * v1.y);
        A.u4[3] = cvt_pk_bf16(hi[6] * v1.z, hi[7] * v1.w);
        f32x4 c0 = {0.f, 0.f, 0.f, 0.f}, c1 = {0.f, 0.f, 0.f, 0.f};
        c0 = __builtin_amdgcn_mfma_f32_16x16x32_bf16(B0.v, A.v, c0, 0, 0, 0);
        c1 = __builtin_amdgcn_mfma_f32_16x16x32_bf16(B1.v, A.v, c1, 0, 0, 0);
        float part = 0.f;
        #pragma unroll
        for (int r = 0; r < 4; r++) {
            part = fmaf(awv0[r], tanh_fast(c0[r] + abv0[r]), part);
            part = fmaf(awv1[r], tanh_fast(c1[r] + abv1[r]), part);
        }
        part += __shfl_xor(part, 16, 64);
        part += __shfl_xor(part, 32, 64);
        sc[q] = part;
    }
    // half-local max + sum
    float mh = -1e30f;
    #pragma unroll
    for (int q = 0; q < 8; q++) mh = fmaxf(mh, sc[q]);
    #pragma unroll
    for (int off = 1; off < 16; off <<= 1) mh = fmaxf(mh, __shfl_xor(mh, off, 64));
    float sh = 0.f;
    #pragma unroll
    for (int q = 0; q < 8; q++) { sc[q] = __expf(sc[q] - mh); sh += sc[q]; }
    #pragma unroll
    for (int off = 1; off < 16; off <<= 1) sh += __shfl_xor(sh, off, 64);
    // PV partial (unnormalized)
    float attp[8] = {0.f, 0.f, 0.f, 0.f, 0.f, 0.f, 0.f, 0.f};
    #pragma unroll
    for (int q = 0; q < 8; q++) {
        int jt = hf * 8 + q;
        const float4* hjp = (const float4*)(h + ((size_t)jt * 16 + n) * 32 + kc);
        float4 v0 = hjp[0], v1 = hjp[1];
        float p = sc[q];
        attp[0] = fmaf(p, v0.x, attp[0]); attp[1] = fmaf(p, v0.y, attp[1]);
        attp[2] = fmaf(p, v0.z, attp[2]); attp[3] = fmaf(p, v0.w, attp[3]);
        attp[4] = fmaf(p, v1.x, attp[4]); attp[5] = fmaf(p, v1.y, attp[5]);
        attp[6] = fmaf(p, v1.z, attp[6]); attp[7] = fmaf(p, v1.w, attp[7]);
    }
    #pragma unroll
    for (int off = 1; off < 16; off <<= 1) {
        #pragma unroll
        for (int e = 0; e < 8; e++) attp[e] += __shfl_xor(attp[e], off, 64);
    }
    // write per-half state to LDS
    if (n == 0) {
        #pragma unroll
        for (int e = 0; e < 8; e++) lds[w][2 + g * 8 + e] = attp[e];
    }
    if (lane == 0) { lds[w][0] = mh; lds[w][1] = sh; }
    __syncthreads();
    // combine: half-0 wave of each row finishes it
    if (hf == 0) {
        int wp = w + 1;
        float m0 = lds[w][0],  s0 = lds[w][1];
        float m1 = lds[wp][0], s1 = lds[wp][1];
        float Mx = fmaxf(m0, m1);
        float e0 = __expf(m0 - Mx), e1 = __expf(m1 - Mx);
        float inv = 1.f / (s0 * e0 + s1 * e1);
        float hif[32];
        #pragma unroll
        for (int gg = 0; gg < 4; gg++) {
            #pragma unroll
            for (int e = 0; e < 8; e++) hif[gg * 8 + e] = __shfl(hi[e], gg << 4, 64);
        }
        int d = lane & 31;
        float z = G[G_PWB + d] + G[G_POB + d];
        #pragma unroll
        for (int c = 0; c < 32; c++) {
            float att = (lds[w][2 + c] * e0 + lds[wp][2 + c] * e1) * inv;
            z = fmaf(G[G_PWW + d * 32 + c], att, fmaf(G[G_POW + d * 32 + c], hif[c], z));
        }
        z = z * G[G_GS + d] + G[G_GB + d];
        z = SELU_L * ((z > 0.f) ? z : SELU_A * (__expf(z) - 1.f));
        if (lane < 32) out[(size_t)i * 32 + d] = z;
    }
}

// ---------------- K5: top-k pooling (rank-select) ----------------
__global__ __launch_bounds__(256) void k5_pool(const float* __restrict__ P,
                                               const float* __restrict__ FCgat,
                                               const float* __restrict__ TCgat,
                                               float* __restrict__ XF,
                                               float* __restrict__ XT) {
    __shared__ float s[256];
    int bi = blockIdx.x;
    int N, kn, b, pboff; const float* g; float* xp; const float* pw;
    if (bi < 16) { b = bi; N = 128; kn = 64;
        g = FCgat + (size_t)b * 4096; xp = XF + (size_t)b * 2048; pw = P + P_PFW; pboff = P_PFB; }
    else { b = bi - 16; N = 256; kn = 128;
        g = TCgat + (size_t)b * 8192; xp = XT + (size_t)b * 4096; pw = P + P_PTW; pboff = P_PTB; }
    int tid = threadIdx.x;
    float sv = 0.f;
    if (tid < N) {
        float z = P[pboff];
        #pragma unroll
        for (int d = 0; d < 32; d++) z = fmaf(pw[d], g[(size_t)tid * 32 + d], z);
        sv = 1.f / (1.f + __expf(-z));
        s[tid] = sv;
    }
    __syncthreads();
    if (tid < N) {
        int rank = 0;
        for (int l = 0; l < N; l++) {
            float sl = s[l];
            rank += (sl > sv) || (sl == sv && l < tid);
        }
        if (rank < kn) {
            #pragma unroll
            for (int d = 0; d < 32; d++) xp[(size_t)rank * 32 + d] = g[(size_t)tid * 32 + d] * sv;
        }
    }
}

// ---------------- K6: cross fusion (wave per output row) ----------------
__global__ __launch_bounds__(256) void k6_fuse(const float* __restrict__ P,
                                               const float* __restrict__ XF,
                                               const float* __restrict__ XT,
                                               float* __restrict__ XFF,
                                               float* __restrict__ XTF) {
    int wid = blockIdx.x * 4 + (threadIdx.x >> 6);
    int lane = threadIdx.x & 63;
    if (wid < 1024) {
        int b = wid >> 6, i = wid & 63;
        const float* xf  = XF + ((size_t)b * 64 + i) * 32;
        const float* xtb = XT + (size_t)b * 4096;
        const float* w1 = P + P_W1;
        int d = lane & 31;
        float y = 0.f;
        #pragma unroll
        for (int c = 0; c < 32; c++) y = fmaf(w1[d * 32 + c], xf[c], y);
        float xtr0[32], xtr1[32];
        #pragma unroll
        for (int c = 0; c < 32; c++) {
            xtr0[c] = xtb[(size_t)lane * 32 + c];
            xtr1[c] = xtb[(size_t)(lane + 64) * 32 + c];
        }
        float s0 = 0.f, s1 = 0.f;
        #pragma unroll
        for (int c = 0; c < 32; c++) {
            float yc = __shfl(y, c, 64);
            s0 = fmaf(yc, xtr0[c], s0);
            s1 = fmaf(yc, xtr1[c], s1);
        }
        float mx = fmaxf(s0, s1);
        #pragma unroll
        for (int off = 1; off < 64; off <<= 1) mx = fmaxf(mx, __shfl_xor(mx, off, 64));
        float e0 = __expf(s0 - mx), e1 = __expf(s1 - mx);
        float sm = e0 + e1;
        #pragma unroll
        for (int off = 1; off < 64; off <<= 1) sm += __shfl_xor(sm, off, 64);
        float inv = 1.f / sm;
        float a0 = e0 * inv, a1 = e1 * inv;
        float v[32];
        #pragma unroll
        for (int c = 0; c < 32; c++) v[c] = a0 * xtr0[c] + a1 * xtr1[c];
        #pragma unroll
        for (int off = 1; off < 64; off <<= 1) {
            #pragma unroll
            for (int c = 0; c < 32; c++) v[c] += __shfl_xor(v[c], off, 64);
        }
        if (lane == 0) {
            float* o = XFF + ((size_t)b * 64 + i) * 32;
            #pragma unroll
            for (int c = 0; c < 32; c++) o[c] = xf[c] + v[c];
        }
    } else {
        int r = wid - 1024;
        int b = r >> 7, i = r & 127;
        const float* xt  = XT + ((size_t)b * 128 + i) * 32;
        const float* xfb = XF + (size_t)b * 2048;
        const float* w2 = P + P_W2;
        int d = lane & 31;
        float y = 0.f;
        #pragma unroll
        for (int c = 0; c < 32; c++) y = fmaf(w2[d * 32 + c], xt[c], y);
        float xfr[32];
        #pragma unroll
        for (int c = 0; c < 32; c++) xfr[c] = xfb[(size_t)lane * 32 + c];
        float sc0 = 0.f;
        #pragma unroll
        for (int c = 0; c < 32; c++) sc0 = fmaf(__shfl(y, c, 64), xfr[c], sc0);
        float mx = sc0;
        #pragma unroll
        for (int off = 1; off < 64; off <<= 1) mx = fmaxf(mx, __shfl_xor(mx, off, 64));
        float e = __expf(sc0 - mx);
        float sm = e;
        #pragma unroll
        for (int off = 1; off < 64; off <<= 1) sm += __shfl_xor(sm, off, 64);
        float a = e / sm;
        float v[32];
        #pragma unroll
        for (int c = 0; c < 32; c++) v[c] = a * xfr[c];
        #pragma unroll
        for (int off = 1; off < 64; off <<= 1) {
            #pragma unroll
            for (int c = 0; c < 32; c++) v[c] += __shfl_xor(v[c], off, 64);
        }
        if (lane == 0) {
            float* o = XTF + ((size_t)b * 128 + i) * 32;
            #pragma unroll
            for (int c = 0; c < 32; c++) o[c] = xt[c] + v[c];
        }
    }
}

// ---------------- K7: row-max + final FC (dtype-aware output) ----------------
__global__ __launch_bounds__(64) void k7_out(const float* __restrict__ P,
                                             const float* __restrict__ XFF,
                                             const float* __restrict__ XTF,
                                             void* __restrict__ outp) {
    __shared__ float node[64];
    int b = blockIdx.x, tid = threadIdx.x;
    if (tid < 32) {
        float m = -1e30f;
        for (int r = 0; r < 64; r++) m = fmaxf(m, XFF[((size_t)b * 64 + r) * 32 + tid]);
        node[tid] = m;
    } else {
        int c = tid - 32;
        float m = -1e30f;
        for (int r = 0; r < 128; r++) m = fmaxf(m, XTF[((size_t)b * 128 + r) * 32 + c]);
        node[tid] = m;
    }
    __syncthreads();
    if (tid < 2) {
        float z = P[P_FCB + tid];
        #pragma unroll
        for (int k = 0; k < 64; k++) z = fmaf(P[P_FCW + tid * 64 + k], node[k], z);
        int isb = (int)P[P_FLAG];
        if (isb) ((u16*)outp)[b * 2 + tid] = f2bf(z);
        else     ((float*)outp)[b * 2 + tid] = z;
    }
}

// ---------------- launch ----------------
extern "C" void kernel_launch(void* const* d_in, const int* in_sizes, int n_in,
                              void* d_out, int out_size, void* d_ws, size_t ws_size,
                              hipStream_t stream) {
    (void)in_sizes; (void)n_in; (void)out_size; (void)ws_size;
    float* W = (float*)d_ws;
    Ptrs ptrs;
    for (int i = 0; i < 39; i++) ptrs.p[i] = d_in[i];
    const void* x = d_in[0];
    float* P = W;

    k0_setup<<<4, 256, 0, stream>>>(ptrs, P);
    k1_conv_m<<<2048, 256, 0, stream>>>(x, P, W + WS_M);
    k2_softmax<<<128, 256, 0, stream>>>(W + WS_M, W + WS_FCATT);
    k3n<<<512, 256, 0, stream>>>(x, W + WS_M, P, W + WS_FCATT, W + WS_TCATT);
    k4ab<<<2560, 256, 0, stream>>>(P, W + WS_FCATT, W + WS_TCATT,
                                   W + WS_FCGAT, W + WS_TCGAT);
    k5_pool<<<32, 256, 0, stream>>>(P, W + WS_FCGAT, W + WS_TCGAT, W + WS_XF, W + WS_XT);
    k6_fuse<<<768, 256, 0, stream>>>(P, W + WS_XF, W + WS_XT, W + WS_XFF, W + WS_XTF);
    k7_out<<<16, 64, 0, stream>>>(P, W + WS_XFF, W + WS_XTF, d_out);
}